// Round 1
// baseline (621.457 us; speedup 1.0000x reference)
//
#include <hip/hip_runtime.h>
#include <math.h>

// Winograd F(5,3) along width + direct 3-tap along height, quantized epilogue.
// N=32, C_IN=64, C_OUT=192, HW=56, 12 tiles of 5 outputs (60->56).

#define NBATCH 32
#define CIN    64
#define COUT   192
#define HWD    56

// ---------------- Kernel 1: solve BT (7x7) via Householder QR in f64 ----------------
__global__ void compute_bt_kernel(float* __restrict__ bt) {
    if (threadIdx.x != 0) return;
    const double ATd[5][7] = {
        {1,1,1,1,1,1,0},{0,1,-1,2,-2,3,0},{0,1,1,4,4,9,0},{0,1,-1,8,-8,27,0},{0,1,1,16,16,81,1}};
    const double pts[6] = {0.0,1.0,-1.0,2.0,-2.0,3.0};
    double G[7][3];
    for (int i=0;i<6;i++){ G[i][0]=1.0; G[i][1]=pts[i]; G[i][2]=pts[i]*pts[i]; }
    G[6][0]=0.0; G[6][1]=0.0; G[6][2]=1.0;
    double M[15][7], T[15][7];
    for (int p=0;p<3;p++)
        for (int u=0;u<5;u++)
            for (int v=0;v<7;v++)
                M[5*p+u][v] = ATd[u][v]*G[v][p];
    for (int i=0;i<15;i++) for (int j=0;j<7;j++) T[i][j]=0.0;
    for (int p=0;p<3;p++) for (int kk=0;kk<5;kk++) T[5*p+kk][kk+p]=1.0;
    // Householder QR
    for (int j=0;j<7;j++){
        double sig=0.0; for (int i=j;i<15;i++) sig += M[i][j]*M[i][j];
        double nrm = sqrt(sig);
        double ajj = M[j][j];
        double alpha = (ajj > 0.0) ? -nrm : nrm;
        double v[15];
        v[j] = ajj - alpha;
        for (int i=j+1;i<15;i++) v[i] = M[i][j];
        double vtv = sig - 2.0*alpha*ajj + alpha*alpha;
        if (vtv > 1e-300) {
            double tau = 2.0/vtv;
            for (int c=j;c<7;c++){
                double s=0.0; for (int i=j;i<15;i++) s += v[i]*M[i][c];
                s *= tau;
                for (int i=j;i<15;i++) M[i][c] -= s*v[i];
            }
            for (int c=0;c<7;c++){
                double s=0.0; for (int i=j;i<15;i++) s += v[i]*T[i][c];
                s *= tau;
                for (int i=j;i<15;i++) T[i][c] -= s*v[i];
            }
        }
        M[j][j] = alpha;
        for (int i=j+1;i<15;i++) M[i][j]=0.0;
    }
    // back substitution: R x = (Q^T T) top rows, per column
    for (int c=0;c<7;c++){
        double xs[7];
        for (int i=6;i>=0;i--){
            double s = T[i][c];
            for (int k2=i+1;k2<7;k2++) s -= M[i][k2]*xs[k2];
            xs[i] = s / M[i][i];
        }
        for (int i=0;i<7;i++) bt[i*7+c] = (float)xs[i];
    }
}

// ---------------- Kernel 2: weight transform wt[cr][o][v8] ----------------
__global__ void wt_kernel(const float* __restrict__ w, float* __restrict__ wt) {
    int idx = blockIdx.x*256 + threadIdx.x;
    if (idx >= COUT*CIN*3) return;
    int o = idx/(CIN*3);
    int rem = idx%(CIN*3);
    int c = rem/3, r = rem%3;
    const float* wp = w + (((size_t)o*CIN + c)*3 + r)*3;
    float w0=wp[0], w1=wp[1], w2=wp[2];
    const float Gf[7][3] = {{1,0,0},{1,1,1},{1,-1,1},{1,2,4},{1,-2,4},{1,3,9},{0,0,1}};
    int cr = c*3 + r;
    float* outp = wt + ((size_t)cr*COUT + o)*8;
    #pragma unroll
    for (int v=0;v<7;v++){
        float val = w0*Gf[v][0] + w1*Gf[v][1] + w2*Gf[v][2];
        val = rintf(val);
        val = fminf(fmaxf(val, -32768.f), 32767.f);
        outp[v] = val;
    }
    outp[7] = 0.f;
}

// ---------------- Kernel 3: fused E-transform + contraction + epilogue ----------------
__global__ __launch_bounds__(192)
void winograd_main(const float* __restrict__ x, const float* __restrict__ wt,
                   const float* __restrict__ bt, const float* __restrict__ alpha,
                   const float* __restrict__ beta, const float* __restrict__ sfp,
                   const float* __restrict__ sop, float* __restrict__ out) {
    const int k = blockIdx.x;   // output row 0..55
    const int n = blockIdx.y;   // batch
    const int tid = threadIdx.x; // = output channel o
    __shared__ float smem[3*64*7*12]; // E: [r][c][v][t], 64512 B; reused for Y [192][56]

    // ---- Stage 1: compute E rows k..k+2 into LDS ----
    float btr[7][7];
    #pragma unroll
    for (int v=0;v<7;v++)
        #pragma unroll
        for (int w=0;w<7;w++) btr[v][w] = bt[v*7+w];

    #pragma unroll 1
    for (int it=0; it<12; ++it) {           // 2304 items / 192 threads
        int item = it*192 + tid;
        int c = item/36, rm = item%36;
        int r = rm/12, t = rm%12;
        int xr = k + r - 1;                  // source x row
        const float* xrow = x + (((size_t)n*CIN + c)*HWD + xr)*HWD;
        float xv[7];
        #pragma unroll
        for (int w=0;w<7;w++){
            int col = 5*t + w - 1;
            bool ok = (xr>=0) & (xr<HWD) & (col>=0) & (col<HWD);
            xv[w] = ok ? xrow[col] : 0.f;
        }
        float* ebase = &smem[((r*64+c)*7)*12 + t];
        #pragma unroll
        for (int v=0;v<7;v++){
            float e = 0.f;
            #pragma unroll
            for (int w=0;w<7;w++) e = fmaf(btr[v][w], xv[w], e);
            e = rintf(e);
            e = fminf(fmaxf(e, -32768.f), 32767.f);
            ebase[v*12] = e;
        }
    }
    __syncthreads();

    // ---- Stage 2: acc[v][t] = sum_{c,r} E[r][c][v][t] * wt[o,c,r,v] ----
    float acc[7][12];
    #pragma unroll
    for (int v=0;v<7;v++)
        #pragma unroll
        for (int t=0;t<12;t++) acc[v][t]=0.f;

    const float* wbase = wt + tid*8;
    float4 wa = *(const float4*)(wbase);
    float4 wb = *(const float4*)(wbase + 4);
    #pragma unroll 1
    for (int cr=0; cr<192; ++cr) {
        int nxt = (cr < 191) ? (cr+1) : 191;
        float4 na = *(const float4*)(wbase + (size_t)nxt*1536);
        float4 nb = *(const float4*)(wbase + (size_t)nxt*1536 + 4);
        const int r = cr % 3, c = cr / 3;
        const float* eb = &smem[((r*64+c)*7)*12];
        float wv[7] = {wa.x, wa.y, wa.z, wa.w, wb.x, wb.y, wb.z};
        #pragma unroll
        for (int v=0;v<7;v++){
            float4 A = *(const float4*)(eb + v*12);
            float4 B = *(const float4*)(eb + v*12 + 4);
            float4 C = *(const float4*)(eb + v*12 + 8);
            float et[12] = {A.x,A.y,A.z,A.w, B.x,B.y,B.z,B.w, C.x,C.y,C.z,C.w};
            #pragma unroll
            for (int t=0;t<12;t++) acc[v][t] = fmaf(wv[v], et[t], acc[v][t]);
        }
        wa = na; wb = nb;
    }

    // ---- Epilogue: AT, quantize, relu; transpose through LDS for coalesced writes ----
    const float ATf[5][7] = {
        {1,1,1,1,1,1,0},{0,1,-1,2,-2,3,0},{0,1,1,4,4,9,0},{0,1,-1,8,-8,27,0},{0,1,1,16,16,81,1}};
    const float denom = 120.f * sfp[0];
    const float av = alpha[tid];
    const float bterm = rintf(beta[tid] * sop[0]);

    __syncthreads();   // all threads done reading E before overwrite

    #pragma unroll
    for (int t=0;t<12;t++){
        #pragma unroll
        for (int u=0;u<5;u++){
            int col = t*5+u;
            if (col < HWD) {
                float y = 0.f;
                #pragma unroll
                for (int v=0;v<7;v++) y = fmaf(ATf[u][v], acc[v][t], y);
                y = rintf(y / denom);
                y = rintf(av * y) + bterm;
                y = rintf(y);
                y = fminf(fmaxf(y, -128.f), 127.f);
                y = fmaxf(y, 0.f);
                smem[tid*HWD + col] = y;   // Y[o][col]
            }
        }
    }
    __syncthreads();

    // cooperative coalesced write: out[n][o][k][col]
    float* ob = out + ((size_t)n*COUT)*HWD*HWD + (size_t)k*HWD;
    #pragma unroll 1
    for (int i=tid; i<COUT*HWD; i+=192) {
        int o = i/HWD, col = i%HWD;
        ob[(size_t)o*HWD*HWD + col] = smem[i];
    }
}

extern "C" void kernel_launch(void* const* d_in, const int* in_sizes, int n_in,
                              void* d_out, int out_size, void* d_ws, size_t ws_size,
                              hipStream_t stream) {
    const float* x      = (const float*)d_in[0];
    const float* weight = (const float*)d_in[1];
    const float* alpha  = (const float*)d_in[2];
    const float* beta   = (const float*)d_in[3];
    const float* sf     = (const float*)d_in[4];
    const float* so     = (const float*)d_in[5];
    float* out = (float*)d_out;

    float* ws_bt = (float*)d_ws;            // 49 floats (use 256 for alignment)
    float* ws_wt = (float*)d_ws + 256;      // 192*192*8 = 294912 floats

    compute_bt_kernel<<<1, 64, 0, stream>>>(ws_bt);
    wt_kernel<<<(COUT*CIN*3 + 255)/256, 256, 0, stream>>>(weight, ws_wt);
    dim3 grid(HWD, NBATCH);
    winograd_main<<<grid, 192, 0, stream>>>(x, ws_wt, ws_bt, alpha, beta, sf, so, out);
}

// Round 2
// 401.176 us; speedup vs baseline: 1.5491x; 1.5491x over previous
//
#include <hip/hip_runtime.h>
#include <math.h>

typedef _Float16 f16x8 __attribute__((ext_vector_type(8)));
typedef float f32x4 __attribute__((ext_vector_type(4)));

#define NBATCH 32
#define CIN    64
#define COUT   192
#define HWD    56
#define KR     4
#define NKQ    14      // 56/KR
#define EROWS  58

// ws layout (bytes)
#define WS_BT_OFF   0
#define WS_W_OFF    1024
#define WS_W_BYTES  (7*COUT*3*CIN*2)                 // 516096
#define WS_EH_OFF   (WS_W_OFF + WS_W_BYTES)
#define EPLANE_ELEMS ((size_t)NBATCH*7*EROWS*12*64)  // 9977856
#define WS_EL_OFF   (WS_EH_OFF + (size_t)EPLANE_ELEMS*2)
#define WS_NEED     (WS_EL_OFF + (size_t)EPLANE_ELEMS*2)

// GEMM LDS layout
#define LDSBUF 24576
#define OFF_AH 0
#define OFF_AL 6144
#define OFF_B  12288

// ---------------- Kernel 1: solve BT (7x7) via Householder QR in f64 ----------------
__global__ void compute_bt_kernel(float* __restrict__ bt) {
    if (threadIdx.x != 0) return;
    const double ATd[5][7] = {
        {1,1,1,1,1,1,0},{0,1,-1,2,-2,3,0},{0,1,1,4,4,9,0},{0,1,-1,8,-8,27,0},{0,1,1,16,16,81,1}};
    const double pts[6] = {0.0,1.0,-1.0,2.0,-2.0,3.0};
    double G[7][3];
    for (int i=0;i<6;i++){ G[i][0]=1.0; G[i][1]=pts[i]; G[i][2]=pts[i]*pts[i]; }
    G[6][0]=0.0; G[6][1]=0.0; G[6][2]=1.0;
    double M[15][7], T[15][7];
    for (int p=0;p<3;p++)
        for (int u=0;u<5;u++)
            for (int v=0;v<7;v++)
                M[5*p+u][v] = ATd[u][v]*G[v][p];
    for (int i=0;i<15;i++) for (int j=0;j<7;j++) T[i][j]=0.0;
    for (int p=0;p<3;p++) for (int kk=0;kk<5;kk++) T[5*p+kk][kk+p]=1.0;
    for (int j=0;j<7;j++){
        double sig=0.0; for (int i=j;i<15;i++) sig += M[i][j]*M[i][j];
        double nrm = sqrt(sig);
        double ajj = M[j][j];
        double alpha = (ajj > 0.0) ? -nrm : nrm;
        double v[15];
        v[j] = ajj - alpha;
        for (int i=j+1;i<15;i++) v[i] = M[i][j];
        double vtv = sig - 2.0*alpha*ajj + alpha*alpha;
        if (vtv > 1e-300) {
            double tau = 2.0/vtv;
            for (int c=j;c<7;c++){
                double s=0.0; for (int i=j;i<15;i++) s += v[i]*M[i][c];
                s *= tau;
                for (int i=j;i<15;i++) M[i][c] -= s*v[i];
            }
            for (int c=0;c<7;c++){
                double s=0.0; for (int i=j;i<15;i++) s += v[i]*T[i][c];
                s *= tau;
                for (int i=j;i<15;i++) T[i][c] -= s*v[i];
            }
        }
        M[j][j] = alpha;
        for (int i=j+1;i<15;i++) M[i][j]=0.0;
    }
    for (int c=0;c<7;c++){
        double xs[7];
        for (int i=6;i>=0;i--){
            double s = T[i][c];
            for (int k2=i+1;k2<7;k2++) s -= M[i][k2]*xs[k2];
            xs[i] = s / M[i][i];
        }
        for (int i=0;i<7;i++) bt[i*7+c] = (float)xs[i];
    }
}

// ---------------- Kernel 2 (fast path): weight transform -> fp16 W[v][o][r][c] ----------------
__global__ void wt16_kernel(const float* __restrict__ w, _Float16* __restrict__ W) {
    int idx = blockIdx.x*256 + threadIdx.x;
    if (idx >= 7*COUT*3*CIN) return;
    int c = idx & 63;
    int r = (idx >> 6) % 3;
    int o = (idx / (64*3)) % COUT;
    int v = idx / (64*3*COUT);
    const float* wp = w + (((size_t)o*CIN + c)*3 + r)*3;
    const float Gf[7][3] = {{1,0,0},{1,1,1},{1,-1,1},{1,2,4},{1,-2,4},{1,3,9},{0,0,1}};
    float val = wp[0]*Gf[v][0] + wp[1]*Gf[v][1] + wp[2]*Gf[v][2];
    val = rintf(val);
    val = fminf(fmaxf(val, -32768.f), 32767.f);   // |val| <= 1664 in practice: exact fp16
    W[idx] = (_Float16)val;
}

// ---------------- Kernel 3 (fast path): E transform -> fp16 planes Eh(=eh*2048), El ----------------
__global__ __launch_bounds__(768)
void e_kernel(const float* __restrict__ x, const float* __restrict__ bt,
              _Float16* __restrict__ Eh, _Float16* __restrict__ El) {
    const int kr = blockIdx.x;   // 0..57 (xp row)
    const int n  = blockIdx.y;
    const int tid = threadIdx.x;
    __shared__ float xs[64][57];
    const int xr = kr - 1;
    const bool rowok = (xr >= 0) && (xr < HWD);
    if (rowok) {
        for (int i = tid; i < 64*56; i += 768) {
            int c = i/56, wcol = i%56;
            xs[c][wcol] = x[(((size_t)n*CIN + c)*HWD + xr)*HWD + wcol];
        }
    }
    __syncthreads();
    float btr[7][7];
    #pragma unroll
    for (int v=0;v<7;v++)
        #pragma unroll
        for (int w2=0;w2<7;w2++) btr[v][w2] = bt[v*7+w2];
    const int t = tid >> 6, c = tid & 63;
    float xv[7];
    #pragma unroll
    for (int ww=0; ww<7; ++ww) {
        int wcol = 5*t + ww - 1;
        float val = 0.f;
        if (rowok && wcol >= 0 && wcol < HWD) val = xs[c][wcol];
        xv[ww] = val;
    }
    const size_t vstr = (size_t)EROWS*12*64;
    size_t base = (((size_t)n*7*EROWS + kr)*12 + t)*64 + c;
    #pragma unroll
    for (int v=0; v<7; ++v) {
        float e = 0.f;
        #pragma unroll
        for (int ww=0; ww<7; ++ww) e = fmaf(btr[v][ww], xv[ww], e);
        e = rintf(e);
        e = fminf(fmaxf(e, -32768.f), 32767.f);
        float eh = rintf(e * (1.f/2048.f));   // eh in [-16,16]
        float el = e - eh*2048.f;             // el in [-1024,1024], exact fp16
        Eh[base + v*vstr] = (_Float16)(eh*2048.f);  // exact fp16 (exponent shift)
        El[base + v*vstr] = (_Float16)el;
    }
}

// ---------------- Kernel 4 (fast path): MFMA GEMM + AT fold + epilogue ----------------
__device__ __forceinline__ void gload16(const void* g, void* l) {
    __builtin_amdgcn_global_load_lds((const __attribute__((address_space(1))) void*)g,
                                     (__attribute__((address_space(3))) void*)l, 16, 0, 0);
}

__device__ __forceinline__ void stage_step(char* ldsbase, int s,
        const _Float16* __restrict__ Eh, const _Float16* __restrict__ El,
        const _Float16* __restrict__ W, int n, int k0, int tid) {
    const int v = s/6, rem = s%6, rr = rem >> 1, c0 = (rem & 1)*32;
    // instruction 1: waves 0-2 -> Ah, waves 3-5 -> Al, waves 6-11 -> B chunks 0..383
    {
        int which, chunk;
        if (tid < 192)      { which = 0; chunk = tid; }
        else if (tid < 384) { which = 1; chunk = tid - 192; }
        else                { which = 2; chunk = tid - 384; }
        int row = chunk >> 2, sl = chunk & 3;
        int g = sl ^ (row & 3) ^ ((row >> 2) & 1);
        if (which == 2) {
            const _Float16* src = W + (((size_t)v*COUT + row)*3 + rr)*64 + c0 + g*8;
            gload16(src, ldsbase + OFF_B + chunk*16);
        } else {
            int krow = k0 + row/12 + rr;
            int t = row % 12;
            size_t idx = ((((size_t)n*7 + v)*EROWS + krow)*12 + t)*64 + c0 + g*8;
            const _Float16* src = (which == 0 ? Eh : El) + idx;
            gload16(src, ldsbase + (which == 0 ? OFF_AH : OFF_AL) + chunk*16);
        }
    }
    // instruction 2: waves 0-5 -> B chunks 384..767
    if (tid < 384) {
        int chunk = 384 + tid;
        int row = chunk >> 2, sl = chunk & 3;
        int g = sl ^ (row & 3) ^ ((row >> 2) & 1);
        const _Float16* src = W + (((size_t)v*COUT + row)*3 + rr)*64 + c0 + g*8;
        gload16(src, ldsbase + OFF_B + chunk*16);
    }
}

__global__ __launch_bounds__(768, 3)
void gemm_kernel(const _Float16* __restrict__ Eh, const _Float16* __restrict__ El,
                 const _Float16* __restrict__ W,
                 const float* __restrict__ alpha, const float* __restrict__ beta,
                 const float* __restrict__ sfp, const float* __restrict__ sop,
                 float* __restrict__ out) {
    const int kq = blockIdx.x, n = blockIdx.y;
    const int k0 = kq*KR;
    const int tid = threadIdx.x;
    const int wid = tid >> 6, lane = tid & 63;
    const int l15 = lane & 15, g = lane >> 4;
    __shared__ __align__(16) char lds[57344];

    f32x4 mv[3];
    f32x4 yu[5][3];
    #pragma unroll
    for (int i=0;i<3;i++) mv[i] = f32x4{0.f,0.f,0.f,0.f};
    #pragma unroll
    for (int u=0;u<5;u++)
        #pragma unroll
        for (int i=0;i<3;i++) yu[u][i] = f32x4{0.f,0.f,0.f,0.f};

    const float ATc[5][7] = {
        {1,1,1,1,1,1,0},{0,1,-1,2,-2,3,0},{0,1,1,4,4,9,0},{0,1,-1,8,-8,27,0},{0,1,1,16,16,81,1}};

    const int slot = g ^ (l15 & 3) ^ ((l15 >> 2) & 1);
    const int aoff = l15*64 + slot*16;
    const int o    = wid*16 + l15;
    const int boff = o*64 + slot*16;

    stage_step(lds, 0, Eh, El, W, n, k0, tid);
    __syncthreads();

    #pragma unroll 2
    for (int s=0; s<42; ++s) {
        char* base = lds + (s & 1)*LDSBUF;
        if (s < 41) stage_step(lds + ((s+1) & 1)*LDSBUF, s+1, Eh, El, W, n, k0, tid);
        f16x8 bf = *(const f16x8*)(base + OFF_B + boff);
        #pragma unroll
        for (int mt=0; mt<3; ++mt) {
            f16x8 ah = *(const f16x8*)(base + OFF_AH + mt*1024 + aoff);
            f16x8 al = *(const f16x8*)(base + OFF_AL + mt*1024 + aoff);
            mv[mt] = __builtin_amdgcn_mfma_f32_16x16x32_f16(ah, bf, mv[mt], 0, 0, 0);
            mv[mt] = __builtin_amdgcn_mfma_f32_16x16x32_f16(al, bf, mv[mt], 0, 0, 0);
        }
        if ((s % 6) == 5) {
            int v = s/6;
            #pragma unroll
            for (int u=0;u<5;u++) {
                float a = ATc[u][v];
                #pragma unroll
                for (int mt=0;mt<3;++mt) {
                    yu[u][mt].x += a*mv[mt].x;
                    yu[u][mt].y += a*mv[mt].y;
                    yu[u][mt].z += a*mv[mt].z;
                    yu[u][mt].w += a*mv[mt].w;
                }
            }
            #pragma unroll
            for (int mt=0;mt<3;++mt) mv[mt] = f32x4{0.f,0.f,0.f,0.f};
        }
        __syncthreads();
    }

    // epilogue
    const float denom = 120.f * sfp[0];
    const float av = alpha[o];
    const float bterm = rintf(beta[o]*sop[0]);
    float* ldsf = (float*)lds;
    for (int p=0;p<3;++p) {
        __syncthreads();
        if ((wid >> 2) == p) {
            int olocal = o - p*64;
            #pragma unroll
            for (int mt=0; mt<3; ++mt) {
                #pragma unroll
                for (int q=0; q<4; ++q) {
                    int m = mt*16 + g*4 + q;
                    int k = m/12, t = m%12;
                    float vals[4] = {yu[0][mt][q], yu[1][mt][q], yu[2][mt][q], yu[3][mt][q]};
                    #pragma unroll
                    for (int u=0; u<5; ++u) {
                        int col = t*5 + u;
                        if (col < HWD) {
                            float yv = (u < 4) ? vals[u] : yu[4][mt][q];
                            yv = rintf(yv/denom);
                            yv = rintf(av*yv) + bterm;
                            yv = rintf(yv);
                            yv = fminf(fmaxf(yv, -128.f), 127.f);
                            yv = fmaxf(yv, 0.f);
                            ldsf[(olocal*4 + k)*56 + col] = yv;
                        }
                    }
                }
            }
        }
        __syncthreads();
        for (int i = tid; i < 64*4*56; i += 768) {
            int o2 = i/224, rem2 = i%224;
            int k = rem2/56, col = rem2%56;
            out[(((size_t)n*COUT + (p*64 + o2))*HWD + (k0 + k))*HWD + col] = ldsf[i];
        }
    }
}

// ================= Fallback path (round-1 kernel, used if ws too small) =================
__global__ void wt_kernel(const float* __restrict__ w, float* __restrict__ wt) {
    int idx = blockIdx.x*256 + threadIdx.x;
    if (idx >= COUT*CIN*3) return;
    int o = idx/(CIN*3);
    int rem = idx%(CIN*3);
    int c = rem/3, r = rem%3;
    const float* wp = w + (((size_t)o*CIN + c)*3 + r)*3;
    float w0=wp[0], w1=wp[1], w2=wp[2];
    const float Gf[7][3] = {{1,0,0},{1,1,1},{1,-1,1},{1,2,4},{1,-2,4},{1,3,9},{0,0,1}};
    int cr = c*3 + r;
    float* outp = wt + ((size_t)cr*COUT + o)*8;
    #pragma unroll
    for (int v=0;v<7;v++){
        float val = w0*Gf[v][0] + w1*Gf[v][1] + w2*Gf[v][2];
        val = rintf(val);
        val = fminf(fmaxf(val, -32768.f), 32767.f);
        outp[v] = val;
    }
    outp[7] = 0.f;
}

__global__ __launch_bounds__(192)
void winograd_main(const float* __restrict__ x, const float* __restrict__ wt,
                   const float* __restrict__ bt, const float* __restrict__ alpha,
                   const float* __restrict__ beta, const float* __restrict__ sfp,
                   const float* __restrict__ sop, float* __restrict__ out) {
    const int k = blockIdx.x;
    const int n = blockIdx.y;
    const int tid = threadIdx.x;
    __shared__ float smem[3*64*7*12];
    float btr[7][7];
    #pragma unroll
    for (int v=0;v<7;v++)
        #pragma unroll
        for (int w=0;w<7;w++) btr[v][w] = bt[v*7+w];
    #pragma unroll 1
    for (int it=0; it<12; ++it) {
        int item = it*192 + tid;
        int c = item/36, rm = item%36;
        int r = rm/12, t = rm%12;
        int xr = k + r - 1;
        const float* xrow = x + (((size_t)n*CIN + c)*HWD + xr)*HWD;
        float xv[7];
        #pragma unroll
        for (int w=0;w<7;w++){
            int col = 5*t + w - 1;
            bool ok = (xr>=0) & (xr<HWD) & (col>=0) & (col<HWD);
            xv[w] = ok ? xrow[col] : 0.f;
        }
        float* ebase = &smem[((r*64+c)*7)*12 + t];
        #pragma unroll
        for (int v=0;v<7;v++){
            float e = 0.f;
            #pragma unroll
            for (int w=0;w<7;w++) e = fmaf(btr[v][w], xv[w], e);
            e = rintf(e);
            e = fminf(fmaxf(e, -32768.f), 32767.f);
            ebase[v*12] = e;
        }
    }
    __syncthreads();
    float acc[7][12];
    #pragma unroll
    for (int v=0;v<7;v++)
        #pragma unroll
        for (int t=0;t<12;t++) acc[v][t]=0.f;
    const float* wbase = wt + tid*8;
    float4 wa = *(const float4*)(wbase);
    float4 wb = *(const float4*)(wbase + 4);
    #pragma unroll 1
    for (int cr=0; cr<192; ++cr) {
        int nxt = (cr < 191) ? (cr+1) : 191;
        float4 na = *(const float4*)(wbase + (size_t)nxt*1536);
        float4 nb = *(const float4*)(wbase + (size_t)nxt*1536 + 4);
        const int r = cr % 3, c = cr / 3;
        const float* eb = &smem[((r*64+c)*7)*12];
        float wv[7] = {wa.x, wa.y, wa.z, wa.w, wb.x, wb.y, wb.z};
        #pragma unroll
        for (int v=0;v<7;v++){
            float4 A = *(const float4*)(eb + v*12);
            float4 B = *(const float4*)(eb + v*12 + 4);
            float4 C = *(const float4*)(eb + v*12 + 8);
            float et[12] = {A.x,A.y,A.z,A.w, B.x,B.y,B.z,B.w, C.x,C.y,C.z,C.w};
            #pragma unroll
            for (int t=0;t<12;t++) acc[v][t] = fmaf(wv[v], et[t], acc[v][t]);
        }
        wa = na; wb = nb;
    }
    const float ATf[5][7] = {
        {1,1,1,1,1,1,0},{0,1,-1,2,-2,3,0},{0,1,1,4,4,9,0},{0,1,-1,8,-8,27,0},{0,1,1,16,16,81,1}};
    const float denom = 120.f * sfp[0];
    const float av = alpha[tid];
    const float bterm = rintf(beta[tid] * sop[0]);
    __syncthreads();
    #pragma unroll
    for (int t=0;t<12;t++){
        #pragma unroll
        for (int u=0;u<5;u++){
            int col = t*5+u;
            if (col < HWD) {
                float y = 0.f;
                #pragma unroll
                for (int v=0;v<7;v++) y = fmaf(ATf[u][v], acc[v][t], y);
                y = rintf(y / denom);
                y = rintf(av * y) + bterm;
                y = rintf(y);
                y = fminf(fmaxf(y, -128.f), 127.f);
                y = fmaxf(y, 0.f);
                smem[tid*HWD + col] = y;
            }
        }
    }
    __syncthreads();
    float* ob = out + ((size_t)n*COUT)*HWD*HWD + (size_t)k*HWD;
    #pragma unroll 1
    for (int i=tid; i<COUT*HWD; i+=192) {
        int o = i/HWD, col = i%HWD;
        ob[(size_t)o*HWD*HWD + col] = smem[i];
    }
}

extern "C" void kernel_launch(void* const* d_in, const int* in_sizes, int n_in,
                              void* d_out, int out_size, void* d_ws, size_t ws_size,
                              hipStream_t stream) {
    const float* x      = (const float*)d_in[0];
    const float* weight = (const float*)d_in[1];
    const float* alpha  = (const float*)d_in[2];
    const float* beta   = (const float*)d_in[3];
    const float* sf     = (const float*)d_in[4];
    const float* so     = (const float*)d_in[5];
    float* out = (float*)d_out;
    float* ws_bt = (float*)d_ws;

    if (ws_size >= (size_t)WS_NEED) {
        _Float16* Wp  = (_Float16*)((char*)d_ws + WS_W_OFF);
        _Float16* Ehp = (_Float16*)((char*)d_ws + WS_EH_OFF);
        _Float16* Elp = (_Float16*)((char*)d_ws + WS_EL_OFF);
        compute_bt_kernel<<<1, 64, 0, stream>>>(ws_bt);
        wt16_kernel<<<(7*COUT*3*CIN + 255)/256, 256, 0, stream>>>(weight, Wp);
        e_kernel<<<dim3(EROWS, NBATCH), 768, 0, stream>>>(x, ws_bt, Ehp, Elp);
        gemm_kernel<<<dim3(NKQ, NBATCH), 768, 0, stream>>>(Ehp, Elp, Wp, alpha, beta, sf, so, out);
    } else {
        float* ws_wt = (float*)d_ws + 256;
        compute_bt_kernel<<<1, 64, 0, stream>>>(ws_bt);
        wt_kernel<<<(COUT*CIN*3 + 255)/256, 256, 0, stream>>>(weight, ws_wt);
        dim3 grid(HWD, NBATCH);
        winograd_main<<<grid, 192, 0, stream>>>(x, ws_wt, ws_bt, alpha, beta, sf, so, out);
    }
}

// Round 3
// 135.494 us; speedup vs baseline: 4.5866x; 2.9608x over previous
//
#include <hip/hip_runtime.h>
#include <math.h>

typedef _Float16 f16x8 __attribute__((ext_vector_type(8)));
typedef float f32x4 __attribute__((ext_vector_type(4)));

#define NBATCH 32
#define CIN    64
#define COUT   192
#define HWD    56
#define KR     4
#define NKQ    14      // 56/KR
#define EROWS  58

// ws layout (bytes)
#define WS_BT_OFF   0
#define WS_W_OFF    1024
#define WS_W_BYTES  (7*COUT*3*CIN*2)                 // 516096
#define WS_EH_OFF   (WS_W_OFF + WS_W_BYTES)
#define EPLANE_ELEMS ((size_t)NBATCH*7*EROWS*12*64)  // 9977856
#define WS_EL_OFF   (WS_EH_OFF + (size_t)EPLANE_ELEMS*2)
#define WS_NEED     (WS_EL_OFF + (size_t)EPLANE_ELEMS*2)

// GEMM LDS layout
#define LDSBUF 24576
#define OFF_AH 0
#define OFF_AL 6144
#define OFF_B  12288

// ---------------- Kernel 1: wave-parallel Householder QR in f64 ----------------
// lane = matrix row (0..14 active). Per-lane rows stay in REGISTERS (all loops
// unrolled -> static indices). Reductions via __shfl_xor butterflies.
__device__ __forceinline__ double wsum(double v) {
    #pragma unroll
    for (int m = 32; m >= 1; m >>= 1) v += __shfl_xor(v, m);
    return v;
}

__global__ void compute_bt_kernel(float* __restrict__ bt) {
    const int lane = threadIdx.x;
    const double ATd[5][7] = {
        {1,1,1,1,1,1,0},{0,1,-1,2,-2,3,0},{0,1,1,4,4,9,0},{0,1,-1,8,-8,27,0},{0,1,1,16,16,81,1}};
    const double pts[6] = {0.0,1.0,-1.0,2.0,-2.0,3.0};

    double Mr[7], Tr[7];
    #pragma unroll
    for (int c = 0; c < 7; ++c) { Mr[c] = 0.0; Tr[c] = 0.0; }
    if (lane < 15) {
        const int p = lane / 5, u = lane % 5;
        #pragma unroll
        for (int v = 0; v < 7; ++v) {
            double g = (v < 6) ? ((p == 0) ? 1.0 : (p == 1) ? pts[v] : pts[v]*pts[v])
                               : ((p == 2) ? 1.0 : 0.0);
            Mr[v] = ATd[u][v] * g;
        }
        // T[5p+u][u+p] = 1
        #pragma unroll
        for (int c = 0; c < 7; ++c) Tr[c] = (c == u + p) ? 1.0 : 0.0;
    }

    #pragma unroll
    for (int j = 0; j < 7; ++j) {
        double mj = Mr[j];
        double sig = wsum((lane >= j && lane < 15) ? mj*mj : 0.0);
        double nrm = sqrt(sig);
        double ajj = __shfl(Mr[j], j);
        double alpha = (ajj > 0.0) ? -nrm : nrm;
        double vi = 0.0;
        if (lane == j) vi = ajj - alpha;
        else if (lane > j && lane < 15) vi = mj;
        double vtv = sig - 2.0*alpha*ajj + alpha*alpha;
        double tau = (vtv > 1e-300) ? (2.0 / vtv) : 0.0;
        #pragma unroll
        for (int c = 0; c < 7; ++c) {
            if (c >= j) {
                double s = wsum(vi * Mr[c]) * tau;
                Mr[c] -= s * vi;
            }
        }
        #pragma unroll
        for (int c = 0; c < 7; ++c) {
            double s = wsum(vi * Tr[c]) * tau;
            Tr[c] -= s * vi;
        }
        if (lane == j) Mr[j] = alpha;
        if (lane > j)  Mr[j] = 0.0;
    }

    // back substitution: R xs = QtT column c, one column per lane (7 lanes)
    __shared__ double Rs[7][7], Ts[7][7];
    if (lane < 7) {
        #pragma unroll
        for (int c = 0; c < 7; ++c) { Rs[lane][c] = Mr[c]; Ts[lane][c] = Tr[c]; }
    }
    __syncthreads();
    if (lane < 7) {
        const int c = lane;
        double xs[7];
        #pragma unroll
        for (int i = 6; i >= 0; --i) {
            double s = Ts[i][c];
            #pragma unroll
            for (int k2 = 6; k2 > i; --k2) s -= Rs[i][k2] * xs[k2];
            xs[i] = s / Rs[i][i];
        }
        #pragma unroll
        for (int i = 0; i < 7; ++i) bt[i*7 + c] = (float)xs[i];
    }
}

// ---------------- Kernel 2 (fast path): weight transform -> fp16 W[v][o][r][c] ----------------
__global__ void wt16_kernel(const float* __restrict__ w, _Float16* __restrict__ W) {
    int idx = blockIdx.x*256 + threadIdx.x;
    if (idx >= 7*COUT*3*CIN) return;
    int c = idx & 63;
    int r = (idx >> 6) % 3;
    int o = (idx / (64*3)) % COUT;
    int v = idx / (64*3*COUT);
    const float* wp = w + (((size_t)o*CIN + c)*3 + r)*3;
    const float Gf[7][3] = {{1,0,0},{1,1,1},{1,-1,1},{1,2,4},{1,-2,4},{1,3,9},{0,0,1}};
    float val = wp[0]*Gf[v][0] + wp[1]*Gf[v][1] + wp[2]*Gf[v][2];
    val = rintf(val);
    val = fminf(fmaxf(val, -32768.f), 32767.f);   // |val| <= 1664 in practice: exact fp16
    W[idx] = (_Float16)val;
}

// ---------------- Kernel 3 (fast path): E transform -> fp16 planes Eh(=eh*2048), El ----------------
__global__ __launch_bounds__(768)
void e_kernel(const float* __restrict__ x, const float* __restrict__ bt,
              _Float16* __restrict__ Eh, _Float16* __restrict__ El) {
    const int kr = blockIdx.x;   // 0..57 (xp row)
    const int n  = blockIdx.y;
    const int tid = threadIdx.x;
    __shared__ float xs[64][57];
    const int xr = kr - 1;
    const bool rowok = (xr >= 0) && (xr < HWD);
    if (rowok) {
        for (int i = tid; i < 64*56; i += 768) {
            int c = i/56, wcol = i%56;
            xs[c][wcol] = x[(((size_t)n*CIN + c)*HWD + xr)*HWD + wcol];
        }
    }
    __syncthreads();
    float btr[7][7];
    #pragma unroll
    for (int v=0;v<7;v++)
        #pragma unroll
        for (int w2=0;w2<7;w2++) btr[v][w2] = bt[v*7+w2];
    const int t = tid >> 6, c = tid & 63;
    float xv[7];
    #pragma unroll
    for (int ww=0; ww<7; ++ww) {
        int wcol = 5*t + ww - 1;
        float val = 0.f;
        if (rowok && wcol >= 0 && wcol < HWD) val = xs[c][wcol];
        xv[ww] = val;
    }
    const size_t vstr = (size_t)EROWS*12*64;
    size_t base = (((size_t)n*7*EROWS + kr)*12 + t)*64 + c;
    #pragma unroll
    for (int v=0; v<7; ++v) {
        float e = 0.f;
        #pragma unroll
        for (int ww=0; ww<7; ++ww) e = fmaf(btr[v][ww], xv[ww], e);
        e = rintf(e);
        e = fminf(fmaxf(e, -32768.f), 32767.f);
        float eh = rintf(e * (1.f/2048.f));   // eh in [-16,16]
        float el = e - eh*2048.f;             // el in [-1024,1024], exact fp16
        Eh[base + v*vstr] = (_Float16)(eh*2048.f);  // exact fp16 (exponent shift)
        El[base + v*vstr] = (_Float16)el;
    }
}

// ---------------- Kernel 4 (fast path): MFMA GEMM + AT fold + epilogue ----------------
__device__ __forceinline__ void gload16(const void* g, void* l) {
    __builtin_amdgcn_global_load_lds((const __attribute__((address_space(1))) void*)g,
                                     (__attribute__((address_space(3))) void*)l, 16, 0, 0);
}

__device__ __forceinline__ void stage_step(char* ldsbase, int s,
        const _Float16* __restrict__ Eh, const _Float16* __restrict__ El,
        const _Float16* __restrict__ W, int n, int k0, int tid) {
    const int v = s/6, rem = s%6, rr = rem >> 1, c0 = (rem & 1)*32;
    // instruction 1: waves 0-2 -> Ah, waves 3-5 -> Al, waves 6-11 -> B chunks 0..383
    {
        int which, chunk;
        if (tid < 192)      { which = 0; chunk = tid; }
        else if (tid < 384) { which = 1; chunk = tid - 192; }
        else                { which = 2; chunk = tid - 384; }
        int row = chunk >> 2, sl = chunk & 3;
        int g = sl ^ (row & 3) ^ ((row >> 2) & 1);
        if (which == 2) {
            const _Float16* src = W + (((size_t)v*COUT + row)*3 + rr)*64 + c0 + g*8;
            gload16(src, ldsbase + OFF_B + chunk*16);
        } else {
            int krow = k0 + row/12 + rr;
            int t = row % 12;
            size_t idx = ((((size_t)n*7 + v)*EROWS + krow)*12 + t)*64 + c0 + g*8;
            const _Float16* src = (which == 0 ? Eh : El) + idx;
            gload16(src, ldsbase + (which == 0 ? OFF_AH : OFF_AL) + chunk*16);
        }
    }
    // instruction 2: waves 0-5 -> B chunks 384..767
    if (tid < 384) {
        int chunk = 384 + tid;
        int row = chunk >> 2, sl = chunk & 3;
        int g = sl ^ (row & 3) ^ ((row >> 2) & 1);
        const _Float16* src = W + (((size_t)v*COUT + row)*3 + rr)*64 + c0 + g*8;
        gload16(src, ldsbase + OFF_B + chunk*16);
    }
}

__global__ __launch_bounds__(768, 3)
void gemm_kernel(const _Float16* __restrict__ Eh, const _Float16* __restrict__ El,
                 const _Float16* __restrict__ W,
                 const float* __restrict__ alpha, const float* __restrict__ beta,
                 const float* __restrict__ sfp, const float* __restrict__ sop,
                 float* __restrict__ out) {
    const int kq = blockIdx.x, n = blockIdx.y;
    const int k0 = kq*KR;
    const int tid = threadIdx.x;
    const int wid = tid >> 6, lane = tid & 63;
    const int l15 = lane & 15, g = lane >> 4;
    __shared__ __align__(16) char lds[57344];

    f32x4 mv[3];
    f32x4 yu[5][3];
    #pragma unroll
    for (int i=0;i<3;i++) mv[i] = f32x4{0.f,0.f,0.f,0.f};
    #pragma unroll
    for (int u=0;u<5;u++)
        #pragma unroll
        for (int i=0;i<3;i++) yu[u][i] = f32x4{0.f,0.f,0.f,0.f};

    const float ATc[5][7] = {
        {1,1,1,1,1,1,0},{0,1,-1,2,-2,3,0},{0,1,1,4,4,9,0},{0,1,-1,8,-8,27,0},{0,1,1,16,16,81,1}};

    const int slot = g ^ (l15 & 3) ^ ((l15 >> 2) & 1);
    const int aoff = l15*64 + slot*16;
    const int o    = wid*16 + l15;
    const int boff = o*64 + slot*16;

    stage_step(lds, 0, Eh, El, W, n, k0, tid);
    __syncthreads();

    #pragma unroll 2
    for (int s=0; s<42; ++s) {
        char* base = lds + (s & 1)*LDSBUF;
        if (s < 41) stage_step(lds + ((s+1) & 1)*LDSBUF, s+1, Eh, El, W, n, k0, tid);
        f16x8 bf = *(const f16x8*)(base + OFF_B + boff);
        #pragma unroll
        for (int mt=0; mt<3; ++mt) {
            f16x8 ah = *(const f16x8*)(base + OFF_AH + mt*1024 + aoff);
            f16x8 al = *(const f16x8*)(base + OFF_AL + mt*1024 + aoff);
            mv[mt] = __builtin_amdgcn_mfma_f32_16x16x32_f16(ah, bf, mv[mt], 0, 0, 0);
            mv[mt] = __builtin_amdgcn_mfma_f32_16x16x32_f16(al, bf, mv[mt], 0, 0, 0);
        }
        if ((s % 6) == 5) {
            int v = s/6;
            #pragma unroll
            for (int u=0;u<5;u++) {
                float a = ATc[u][v];
                #pragma unroll
                for (int mt=0;mt<3;++mt) {
                    yu[u][mt].x += a*mv[mt].x;
                    yu[u][mt].y += a*mv[mt].y;
                    yu[u][mt].z += a*mv[mt].z;
                    yu[u][mt].w += a*mv[mt].w;
                }
            }
            #pragma unroll
            for (int mt=0;mt<3;++mt) mv[mt] = f32x4{0.f,0.f,0.f,0.f};
        }
        __syncthreads();
    }

    // epilogue
    const float denom = 120.f * sfp[0];
    const float av = alpha[o];
    const float bterm = rintf(beta[o]*sop[0]);
    float* ldsf = (float*)lds;
    for (int p=0;p<3;++p) {
        __syncthreads();
        if ((wid >> 2) == p) {
            int olocal = o - p*64;
            #pragma unroll
            for (int mt=0; mt<3; ++mt) {
                #pragma unroll
                for (int q=0; q<4; ++q) {
                    int m = mt*16 + g*4 + q;
                    int k = m/12, t = m%12;
                    float vals[4] = {yu[0][mt][q], yu[1][mt][q], yu[2][mt][q], yu[3][mt][q]};
                    #pragma unroll
                    for (int u=0; u<5; ++u) {
                        int col = t*5 + u;
                        if (col < HWD) {
                            float yv = (u < 4) ? vals[u] : yu[4][mt][q];
                            yv = rintf(yv/denom);
                            yv = rintf(av*yv) + bterm;
                            yv = rintf(yv);
                            yv = fminf(fmaxf(yv, -128.f), 127.f);
                            yv = fmaxf(yv, 0.f);
                            ldsf[(olocal*4 + k)*56 + col] = yv;
                        }
                    }
                }
            }
        }
        __syncthreads();
        for (int i = tid; i < 64*4*56; i += 768) {
            int o2 = i/224, rem2 = i%224;
            int k = rem2/56, col = rem2%56;
            out[(((size_t)n*COUT + (p*64 + o2))*HWD + (k0 + k))*HWD + col] = ldsf[i];
        }
    }
}

// ================= Fallback path (round-1 kernel, used if ws too small) =================
__global__ void wt_kernel(const float* __restrict__ w, float* __restrict__ wt) {
    int idx = blockIdx.x*256 + threadIdx.x;
    if (idx >= COUT*CIN*3) return;
    int o = idx/(CIN*3);
    int rem = idx%(CIN*3);
    int c = rem/3, r = rem%3;
    const float* wp = w + (((size_t)o*CIN + c)*3 + r)*3;
    float w0=wp[0], w1=wp[1], w2=wp[2];
    const float Gf[7][3] = {{1,0,0},{1,1,1},{1,-1,1},{1,2,4},{1,-2,4},{1,3,9},{0,0,1}};
    int cr = c*3 + r;
    float* outp = wt + ((size_t)cr*COUT + o)*8;
    #pragma unroll
    for (int v=0;v<7;v++){
        float val = w0*Gf[v][0] + w1*Gf[v][1] + w2*Gf[v][2];
        val = rintf(val);
        val = fminf(fmaxf(val, -32768.f), 32767.f);
        outp[v] = val;
    }
    outp[7] = 0.f;
}

__global__ __launch_bounds__(192)
void winograd_main(const float* __restrict__ x, const float* __restrict__ wt,
                   const float* __restrict__ bt, const float* __restrict__ alpha,
                   const float* __restrict__ beta, const float* __restrict__ sfp,
                   const float* __restrict__ sop, float* __restrict__ out) {
    const int k = blockIdx.x;
    const int n = blockIdx.y;
    const int tid = threadIdx.x;
    __shared__ float smem[3*64*7*12];
    float btr[7][7];
    #pragma unroll
    for (int v=0;v<7;v++)
        #pragma unroll
        for (int w=0;w<7;w++) btr[v][w] = bt[v*7+w];
    #pragma unroll 1
    for (int it=0; it<12; ++it) {
        int item = it*192 + tid;
        int c = item/36, rm = item%36;
        int r = rm/12, t = rm%12;
        int xr = k + r - 1;
        const float* xrow = x + (((size_t)n*CIN + c)*HWD + xr)*HWD;
        float xv[7];
        #pragma unroll
        for (int w=0;w<7;w++){
            int col = 5*t + w - 1;
            bool ok = (xr>=0) & (xr<HWD) & (col>=0) & (col<HWD);
            xv[w] = ok ? xrow[col] : 0.f;
        }
        float* ebase = &smem[((r*64+c)*7)*12 + t];
        #pragma unroll
        for (int v=0;v<7;v++){
            float e = 0.f;
            #pragma unroll
            for (int w=0;w<7;w++) e = fmaf(btr[v][w], xv[w], e);
            e = rintf(e);
            e = fminf(fmaxf(e, -32768.f), 32767.f);
            ebase[v*12] = e;
        }
    }
    __syncthreads();
    float acc[7][12];
    #pragma unroll
    for (int v=0;v<7;v++)
        #pragma unroll
        for (int t=0;t<12;t++) acc[v][t]=0.f;
    const float* wbase = wt + tid*8;
    float4 wa = *(const float4*)(wbase);
    float4 wb = *(const float4*)(wbase + 4);
    #pragma unroll 1
    for (int cr=0; cr<192; ++cr) {
        int nxt = (cr < 191) ? (cr+1) : 191;
        float4 na = *(const float4*)(wbase + (size_t)nxt*1536);
        float4 nb = *(const float4*)(wbase + (size_t)nxt*1536 + 4);
        const int r = cr % 3, c = cr / 3;
        const float* eb = &smem[((r*64+c)*7)*12];
        float wv[7] = {wa.x, wa.y, wa.z, wa.w, wb.x, wb.y, wb.z};
        #pragma unroll
        for (int v=0;v<7;v++){
            float4 A = *(const float4*)(eb + v*12);
            float4 B = *(const float4*)(eb + v*12 + 4);
            float4 C = *(const float4*)(eb + v*12 + 8);
            float et[12] = {A.x,A.y,A.z,A.w, B.x,B.y,B.z,B.w, C.x,C.y,C.z,C.w};
            #pragma unroll
            for (int t=0;t<12;t++) acc[v][t] = fmaf(wv[v], et[t], acc[v][t]);
        }
        wa = na; wb = nb;
    }
    const float ATf[5][7] = {
        {1,1,1,1,1,1,0},{0,1,-1,2,-2,3,0},{0,1,1,4,4,9,0},{0,1,-1,8,-8,27,0},{0,1,1,16,16,81,1}};
    const float denom = 120.f * sfp[0];
    const float av = alpha[tid];
    const float bterm = rintf(beta[tid] * sop[0]);
    __syncthreads();
    #pragma unroll
    for (int t=0;t<12;t++){
        #pragma unroll
        for (int u=0;u<5;u++){
            int col = t*5+u;
            if (col < HWD) {
                float y = 0.f;
                #pragma unroll
                for (int v=0;v<7;v++) y = fmaf(ATf[u][v], acc[v][t], y);
                y = rintf(y / denom);
                y = rintf(av * y) + bterm;
                y = rintf(y);
                y = fminf(fmaxf(y, -128.f), 127.f);
                y = fmaxf(y, 0.f);
                smem[tid*HWD + col] = y;
            }
        }
    }
    __syncthreads();
    float* ob = out + ((size_t)n*COUT)*HWD*HWD + (size_t)k*HWD;
    #pragma unroll 1
    for (int i=tid; i<COUT*HWD; i+=192) {
        int o = i/HWD, col = i%HWD;
        ob[(size_t)o*HWD*HWD + col] = smem[i];
    }
}

extern "C" void kernel_launch(void* const* d_in, const int* in_sizes, int n_in,
                              void* d_out, int out_size, void* d_ws, size_t ws_size,
                              hipStream_t stream) {
    const float* x      = (const float*)d_in[0];
    const float* weight = (const float*)d_in[1];
    const float* alpha  = (const float*)d_in[2];
    const float* beta   = (const float*)d_in[3];
    const float* sf     = (const float*)d_in[4];
    const float* so     = (const float*)d_in[5];
    float* out = (float*)d_out;
    float* ws_bt = (float*)d_ws;

    if (ws_size >= (size_t)WS_NEED) {
        _Float16* Wp  = (_Float16*)((char*)d_ws + WS_W_OFF);
        _Float16* Ehp = (_Float16*)((char*)d_ws + WS_EH_OFF);
        _Float16* Elp = (_Float16*)((char*)d_ws + WS_EL_OFF);
        compute_bt_kernel<<<1, 64, 0, stream>>>(ws_bt);
        wt16_kernel<<<(7*COUT*3*CIN + 255)/256, 256, 0, stream>>>(weight, Wp);
        e_kernel<<<dim3(EROWS, NBATCH), 768, 0, stream>>>(x, ws_bt, Ehp, Elp);
        gemm_kernel<<<dim3(NKQ, NBATCH), 768, 0, stream>>>(Ehp, Elp, Wp, alpha, beta, sf, so, out);
    } else {
        float* ws_wt = (float*)d_ws + 256;
        compute_bt_kernel<<<1, 64, 0, stream>>>(ws_bt);
        wt_kernel<<<(COUT*CIN*3 + 255)/256, 256, 0, stream>>>(weight, ws_wt);
        dim3 grid(HWD, NBATCH);
        winograd_main<<<grid, 192, 0, stream>>>(x, ws_wt, ws_bt, alpha, beta, sf, so, out);
    }
}

// Round 4
// 99.568 us; speedup vs baseline: 6.2415x; 1.3608x over previous
//
#include <hip/hip_runtime.h>
#include <math.h>

typedef _Float16 f16x8 __attribute__((ext_vector_type(8)));
typedef float f32x4 __attribute__((ext_vector_type(4)));
typedef unsigned int u32;
typedef unsigned long long u64;

#define NBATCH 32
#define CIN    64
#define COUT   192
#define HWD    56
#define KR     4
#define NKQ    14

// ---- LDS layout (dynamic, 89088 B) ----
#define XOFF    0
#define XSTRIDE 88
#define XSIZE   (6*64*88)      // 33792
#define EHOFF   33792          // 72 rows * 128 B
#define ELOFF   43008
#define BOFF    52224          // 3 bufs * 12288
#define BBUF    12288
#define LDS_TOTAL 89088

// ws layout
#define WS_BT_OFF 0
#define WS_W_OFF  1024

#define SBAR() do { __builtin_amdgcn_s_barrier(); asm volatile("" ::: "memory"); } while(0)
#define WAITL()  asm volatile("s_waitcnt lgkmcnt(0)" ::: "memory")
#define WAITV1() asm volatile("s_waitcnt vmcnt(1) lgkmcnt(0)" ::: "memory")
#define WAITV0() asm volatile("s_waitcnt vmcnt(0) lgkmcnt(0)" ::: "memory")

// ---------------- Kernel 1: wave-parallel Householder QR (f64) + fp16-range flag ----------------
__device__ __forceinline__ double wsum(double v) {
    #pragma unroll
    for (int m = 32; m >= 1; m >>= 1) v += __shfl_xor(v, m);
    return v;
}

__global__ void compute_bt_kernel(float* __restrict__ bt) {
    const int lane = threadIdx.x;
    const double ATd[5][7] = {
        {1,1,1,1,1,1,0},{0,1,-1,2,-2,3,0},{0,1,1,4,4,9,0},{0,1,-1,8,-8,27,0},{0,1,1,16,16,81,1}};
    const double pts[6] = {0.0,1.0,-1.0,2.0,-2.0,3.0};

    double Mr[7], Tr[7];
    #pragma unroll
    for (int c = 0; c < 7; ++c) { Mr[c] = 0.0; Tr[c] = 0.0; }
    if (lane < 15) {
        const int p = lane / 5, u = lane % 5;
        #pragma unroll
        for (int v = 0; v < 7; ++v) {
            double gg = (v < 6) ? ((p == 0) ? 1.0 : (p == 1) ? pts[v] : pts[v]*pts[v])
                                : ((p == 2) ? 1.0 : 0.0);
            Mr[v] = ATd[u][v] * gg;
        }
        #pragma unroll
        for (int c = 0; c < 7; ++c) Tr[c] = (c == u + p) ? 1.0 : 0.0;
    }

    #pragma unroll
    for (int j = 0; j < 7; ++j) {
        double mj = Mr[j];
        double sig = wsum((lane >= j && lane < 15) ? mj*mj : 0.0);
        double nrm = sqrt(sig);
        double ajj = __shfl(Mr[j], j);
        double alpha = (ajj > 0.0) ? -nrm : nrm;
        double vi = 0.0;
        if (lane == j) vi = ajj - alpha;
        else if (lane > j && lane < 15) vi = mj;
        double vtv = sig - 2.0*alpha*ajj + alpha*alpha;
        double tau = (vtv > 1e-300) ? (2.0 / vtv) : 0.0;
        #pragma unroll
        for (int c = 0; c < 7; ++c) {
            if (c >= j) {
                double s = wsum(vi * Mr[c]) * tau;
                Mr[c] -= s * vi;
            }
        }
        #pragma unroll
        for (int c = 0; c < 7; ++c) {
            double s = wsum(vi * Tr[c]) * tau;
            Tr[c] -= s * vi;
        }
        if (lane == j) Mr[j] = alpha;
        if (lane > j)  Mr[j] = 0.0;
    }

    __shared__ double Rs[7][7], Ts[7][7];
    if (lane < 7) {
        #pragma unroll
        for (int c = 0; c < 7; ++c) { Rs[lane][c] = Mr[c]; Ts[lane][c] = Tr[c]; }
    }
    __syncthreads();
    const int cc = (lane < 7) ? lane : 0;
    double xs[7];
    #pragma unroll
    for (int i = 6; i >= 0; --i) {
        double s = Ts[i][cc];
        #pragma unroll
        for (int k2 = 6; k2 > i; --k2) s -= Rs[i][k2] * xs[k2];
        xs[i] = s / Rs[i][i];
    }
    if (lane < 7) {
        #pragma unroll
        for (int i = 0; i < 7; ++i) bt[i*7 + lane] = (float)xs[i];
    }
    // fp16-single-plane feasibility: max_v sum_w |BT[v][w]| * 128 <= 2048 ?
    double rs[7];
    #pragma unroll
    for (int v = 0; v < 7; ++v)
        rs[v] = wsum((lane < 7) ? fabs(xs[v]) : 0.0);
    if (lane == 0) {
        double mb = 0.0;
        #pragma unroll
        for (int v = 0; v < 7; ++v) mb = fmax(mb, rs[v]);
        bt[49] = (mb * 128.0 <= 2048.0) ? 1.f : 0.f;
    }
}

// ---------------- Kernel 2: weight transform -> fp16 W[v][o][r][c] ----------------
__global__ void wt16_kernel(const float* __restrict__ w, _Float16* __restrict__ W) {
    int idx = blockIdx.x*256 + threadIdx.x;
    if (idx >= 7*COUT*3*CIN) return;
    int c = idx & 63;
    int r = (idx >> 6) % 3;
    int o = (idx / (64*3)) % COUT;
    int v = idx / (64*3*COUT);
    const float* wp = w + (((size_t)o*CIN + c)*3 + r)*3;
    const float Gf[7][3] = {{1,0,0},{1,1,1},{1,-1,1},{1,2,4},{1,-2,4},{1,3,9},{0,0,1}};
    float val = wp[0]*Gf[v][0] + wp[1]*Gf[v][1] + wp[2]*Gf[v][2];
    val = rintf(val);
    val = fminf(fmaxf(val, -32768.f), 32767.f);   // |val| <= 1664: exact fp16
    W[idx] = (_Float16)val;
}

// ---------------- Kernel 3: fused E-transform + MFMA GEMM + AT + epilogue ----------------
__device__ __forceinline__ void gload16(const void* g, void* l) {
    __builtin_amdgcn_global_load_lds((const __attribute__((address_space(1))) void*)g,
                                     (__attribute__((address_space(3))) void*)l, 16, 0, 0);
}

__global__ __launch_bounds__(768, 3)
void main_kernel(const float* __restrict__ x, const _Float16* __restrict__ W,
                 const float* __restrict__ bt,
                 const float* __restrict__ alpha, const float* __restrict__ beta,
                 const float* __restrict__ sfp, const float* __restrict__ sop,
                 float* __restrict__ out)
{
    extern __shared__ char lds[];
    const int kq = blockIdx.x, n = blockIdx.y, k0 = kq*KR;
    const int tid = threadIdx.x;
    const int wid = tid >> 6, lane = tid & 63, l15 = lane & 15, g = lane >> 4;
    const int mg = wid >> 2, ng = wid & 3;
    const bool dual = (bt[49] < 0.5f);

    const int st_o = tid >> 2, st_q = tid & 3;
    auto STAGE = [&](int S){
        int v = S/6, rem = S%6, rr = rem>>1, ch = rem&1;
        const _Float16* src = W + (((v*COUT + st_o)*3 + rr) << 6) + ch*32 + st_q*8;
        gload16(src, lds + BOFF + (S%3)*BBUF + tid*16);
    };

    STAGE(0); STAGE(1);

    // ---- stage x rows (k0-1 .. k0+4) as biased u8 into LDS [6][64][88] ----
    #pragma unroll
    for (int j = 0; j < 7; ++j) {
        int idx = j*768 + tid;                 // < 5376 = 6*64*14
        int krow = idx / 896, rem = idx - krow*896;
        int c = rem / 14, col4 = rem - c*14;
        int xr = k0 + krow - 1;
        u32 bword = 0x80808080u;
        if (xr >= 0 && xr < HWD) {
            const float4 vx = *(const float4*)(x + (((size_t)(n*CIN + c))*HWD + xr)*HWD + col4*4);
            u32 b0 = (u32)(int)(vx.x + 128.f);
            u32 b1 = (u32)(int)(vx.y + 128.f);
            u32 b2 = (u32)(int)(vx.z + 128.f);
            u32 b3 = (u32)(int)(vx.w + 128.f);
            bword = b0 | (b1 << 8) | (b2 << 16) | (b3 << 24);
        }
        *(u32*)(lds + XOFF + (krow*64 + c)*XSTRIDE + 4 + col4*4) = bword;
    }
    #pragma unroll
    for (int jj = 0; jj < 4; ++jj) {           // pads: bytes 0..3 and 60..87 per (krow,c)
        int p = jj*768 + tid;                  // < 3072
        int pr = p >> 3, ws = p & 7;
        int krow = pr >> 6, c = pr & 63;
        int wb = (ws == 0) ? 0 : 56 + ws*4;
        *(u32*)(lds + XOFF + (krow*64 + c)*XSTRIDE + wb) = 0x80808080u;
    }
    __syncthreads();

    // ---- unpack per-thread x window (t = wid, c = lane) into registers ----
    float xf[6][7];
    {
        const int ofs = (5*wid + 3) & 7;
        const int a0  = (5*wid + 3) & ~7;
        const u32 qsel = (u32)(ofs >> 2);
        const u32 r = (u32)((ofs & 3) * 8);
        #pragma unroll
        for (int krow = 0; krow < 6; ++krow) {
            const char* pb = lds + XOFF + (krow*64 + lane)*XSTRIDE + a0;
            uint2 A2 = *(const uint2*)pb;
            uint2 B2 = *(const uint2*)(pb + 8);
            u32 d0 = A2.x, d1 = A2.y, d2 = B2.x, d3 = B2.y;
            u32 e0 = qsel ? d1 : d0, e1 = qsel ? d2 : d1, e2 = qsel ? d3 : d2;
            u64 lo = (((u64)e1 << 32) | e0) >> r;
            u64 hi = (((u64)e2 << 32) | e1) >> r;
            u32 Aw = (u32)lo, Bw = (u32)hi;
            xf[krow][0] = (float)(Aw & 255u);
            xf[krow][1] = (float)((Aw >> 8) & 255u);
            xf[krow][2] = (float)((Aw >> 16) & 255u);
            xf[krow][3] = (float)(Aw >> 24);
            xf[krow][4] = (float)(Bw & 255u);
            xf[krow][5] = (float)((Bw >> 8) & 255u);
            xf[krow][6] = (float)((Bw >> 16) & 255u);
        }
    }

    f32x4 mv[3], yu[5][3];
    #pragma unroll
    for (int i = 0; i < 3; ++i) mv[i] = f32x4{0.f,0.f,0.f,0.f};
    #pragma unroll
    for (int u = 0; u < 5; ++u)
        #pragma unroll
        for (int i = 0; i < 3; ++i) yu[u][i] = f32x4{0.f,0.f,0.f,0.f};

    const float ATc[5][7] = {
        {1,1,1,1,1,1,0},{0,1,-1,2,-2,3,0},{0,1,1,4,4,9,0},{0,1,-1,8,-8,27,0},{0,1,1,16,16,81,1}};

    const int boff0 = (ng*48 +  0 + l15)*64 + g*16;
    const int boff1 = (ng*48 + 16 + l15)*64 + g*16;
    const int boff2 = (ng*48 + 32 + l15)*64 + g*16;

    #pragma unroll
    for (int v = 0; v < 7; ++v) {
        // fold previous v's mv into yu (pure register math)
        if (v > 0) {
            #pragma unroll
            for (int u = 0; u < 5; ++u) {
                const float a = ATc[u][v-1];
                if (a != 0.f) {
                    #pragma unroll
                    for (int fi = 0; fi < 3; ++fi) yu[u][fi] += a * mv[fi];
                }
            }
            #pragma unroll
            for (int fi = 0; fi < 3; ++fi) mv[fi] = f32x4{0.f,0.f,0.f,0.f};
        }
        // pre-E barrier: all threads' A-reads of v-1 drained
        WAITL(); SBAR();

        // E-compute for this v: rows krow*12 + wid, col = lane
        {
            const float b0 = bt[v*7+0], b1 = bt[v*7+1], b2 = bt[v*7+2], b3 = bt[v*7+3];
            const float b4 = bt[v*7+4], b5 = bt[v*7+5], b6 = bt[v*7+6];
            const float einit = -128.f * (b0+b1+b2+b3+b4+b5+b6);
            #pragma unroll
            for (int krow = 0; krow < 6; ++krow) {
                float e = einit;
                e = fmaf(b0, xf[krow][0], e);
                e = fmaf(b1, xf[krow][1], e);
                e = fmaf(b2, xf[krow][2], e);
                e = fmaf(b3, xf[krow][3], e);
                e = fmaf(b4, xf[krow][4], e);
                e = fmaf(b5, xf[krow][5], e);
                e = fmaf(b6, xf[krow][6], e);
                e = rintf(e);
                e = fminf(fmaxf(e, -32768.f), 32767.f);
                const int row = krow*12 + wid;
                const int sbyte = ((((lane>>3) ^ (row&7)) << 4) | ((lane&7) << 1));
                if (dual) {
                    float ehs = rintf(e * (1.f/2048.f)) * 2048.f;
                    float el  = e - ehs;
                    *(_Float16*)(lds + EHOFF + row*128 + sbyte) = (_Float16)ehs;
                    *(_Float16*)(lds + ELOFF + row*128 + sbyte) = (_Float16)el;
                } else {
                    *(_Float16*)(lds + EHOFF + row*128 + sbyte) = (_Float16)e;
                }
            }
        }

        // 6 K-steps for this v
        #pragma unroll
        for (int si = 0; si < 6; ++si) {
            const int S = v*6 + si;
            if (S == 41) { WAITV0(); } else { WAITV1(); }
            SBAR();
            if (S + 2 < 42) STAGE(S + 2);
            const int rr = si >> 1, ch = si & 1;
            const char* bb = lds + BOFF + (S % 3)*BBUF;
            f16x8 bf0 = *(const f16x8*)(bb + boff0);
            f16x8 bf1 = *(const f16x8*)(bb + boff1);
            f16x8 bf2 = *(const f16x8*)(bb + boff2);
            const int arow = rr*12 + mg*16 + l15;
            const int abyte = arow*128 + (((ch*4 + g) ^ (arow & 7)) << 4);
            f16x8 ah = *(const f16x8*)(lds + EHOFF + abyte);
            mv[0] = __builtin_amdgcn_mfma_f32_16x16x32_f16(ah, bf0, mv[0], 0, 0, 0);
            mv[1] = __builtin_amdgcn_mfma_f32_16x16x32_f16(ah, bf1, mv[1], 0, 0, 0);
            mv[2] = __builtin_amdgcn_mfma_f32_16x16x32_f16(ah, bf2, mv[2], 0, 0, 0);
            if (dual) {
                f16x8 al = *(const f16x8*)(lds + ELOFF + abyte);
                mv[0] = __builtin_amdgcn_mfma_f32_16x16x32_f16(al, bf0, mv[0], 0, 0, 0);
                mv[1] = __builtin_amdgcn_mfma_f32_16x16x32_f16(al, bf1, mv[1], 0, 0, 0);
                mv[2] = __builtin_amdgcn_mfma_f32_16x16x32_f16(al, bf2, mv[2], 0, 0, 0);
            }
        }
    }
    // fold v=6
    #pragma unroll
    for (int u = 0; u < 5; ++u) {
        const float a = ATc[u][6];
        if (a != 0.f) {
            #pragma unroll
            for (int fi = 0; fi < 3; ++fi) yu[u][fi] += a * mv[fi];
        }
    }

    WAITL(); SBAR();   // all LDS reads done; reuse LDS for epilogue

    // ---- epilogue: AT done; quantize + transpose via LDS, coalesced writes ----
    const float denom = 120.f * sfp[0];
    float av[3], bt3[3];
    #pragma unroll
    for (int fi = 0; fi < 3; ++fi) {
        int o = ng*48 + fi*16 + l15;
        av[fi]  = alpha[o];
        bt3[fi] = rintf(beta[o] * sop[0]);
    }
    float* ldsf = (float*)lds;    // [192][61]
    #pragma unroll
    for (int klocal = 0; klocal < 4; ++klocal) {
        #pragma unroll
        for (int q = 0; q < 4; ++q) {
            int m = mg*16 + g*4 + q;
            if (m / 12 == klocal) {
                int t = m - klocal*12;
                #pragma unroll
                for (int fi = 0; fi < 3; ++fi) {
                    int o = ng*48 + fi*16 + l15;
                    #pragma unroll
                    for (int u = 0; u < 5; ++u) {
                        float yv = yu[u][fi][q];
                        yv = rintf(yv / denom);
                        yv = rintf(av[fi]*yv) + bt3[fi];
                        yv = rintf(yv);
                        yv = fminf(fmaxf(yv, -128.f), 127.f);
                        yv = fmaxf(yv, 0.f);
                        ldsf[o*61 + t*5 + u] = yv;
                    }
                }
            }
        }
        __syncthreads();
        #pragma unroll
        for (int i = 0; i < 14; ++i) {
            int idx2 = i*768 + tid;            // < 10752 = 192*56
            int o = idx2 / 56, col = idx2 - o*56;
            out[(((size_t)(n*COUT + o))*HWD + (k0 + klocal))*HWD + col] = ldsf[o*61 + col];
        }
        __syncthreads();
    }
}

extern "C" void kernel_launch(void* const* d_in, const int* in_sizes, int n_in,
                              void* d_out, int out_size, void* d_ws, size_t ws_size,
                              hipStream_t stream) {
    const float* x      = (const float*)d_in[0];
    const float* weight = (const float*)d_in[1];
    const float* alpha  = (const float*)d_in[2];
    const float* beta   = (const float*)d_in[3];
    const float* sf     = (const float*)d_in[4];
    const float* so     = (const float*)d_in[5];
    float* out = (float*)d_out;

    float* ws_bt = (float*)((char*)d_ws + WS_BT_OFF);
    _Float16* Wp = (_Float16*)((char*)d_ws + WS_W_OFF);

    (void)hipFuncSetAttribute((const void*)main_kernel,
                              hipFuncAttributeMaxDynamicSharedMemorySize, LDS_TOTAL);

    compute_bt_kernel<<<1, 64, 0, stream>>>(ws_bt);
    wt16_kernel<<<(7*COUT*3*CIN + 255)/256, 256, 0, stream>>>(weight, Wp);
    main_kernel<<<dim3(NKQ, NBATCH), 768, LDS_TOTAL, stream>>>(x, Wp, ws_bt, alpha, beta, sf, so, out);
}